// Round 12
// baseline (258.227 us; speedup 1.0000x reference)
//
#include <hip/hip_runtime.h>

// ---------------------------------------------------------------------------
// TernaryInvertedResidual on MI355X (gfx950) — R16
//
// vs R15 (verified 254.6us): conv1 refined, all else byte-identical.
//   * Pb adopts conv2's verified epilogue-P layout (384B rows,
//     kc*128 + (chunk^(px&7))*16) -> 43008 B instead of 57344.
//   * LDS non-union: {smA 14336 | smB 12288 | Pb 43008} = 69632 B -> still
//     2 blocks/CU, and smA/smB persist through the epilogue: the bv0/bv1
//     REGISTER preload (+~60 VGPR) and one drain barrier are removed —
//     fragments are read per row from persistent smA.
//   * copyout indexing adjusted to the new P layout; identical bytes to
//     identical h1p destinations -> bit-identical output.
// conv2_kernel byte-identical to verified R13/R14/R15.
// stats1 / stats2_pack byte-identical to verified R14/R15.
// ---------------------------------------------------------------------------

typedef __bf16 bf16x8 __attribute__((ext_vector_type(8)));
typedef __bf16 bf16x4 __attribute__((ext_vector_type(4)));
typedef float  f32x4  __attribute__((ext_vector_type(4)));

#define EPSBN 1e-5f

// async global->LDS, 16B per lane; LDS dest = wave-uniform base + lane*16
__device__ __forceinline__ void glds16(const void* g, void* l) {
  __builtin_amdgcn_global_load_lds(
      (const __attribute__((address_space(1))) void*)g,
      (__attribute__((address_space(3))) void*)l, 16, 0, 0);
}

__device__ __forceinline__ __bf16 tern(float w, float delta) {
  float aw = fabsf(w);
  float q = (aw > delta) ? ((w > 0.0f) ? 1.0f : -1.0f) : 0.0f;
  return (__bf16)q;
}

// ---------------- stats pass 1 (abs-sum partials) --------------------------
// tensor index: 0=w1 (6144), 1=w2 (331776), 2=w3 (6144)
__global__ void stats_pass1(const float* __restrict__ w1, const float* __restrict__ w2,
                            const float* __restrict__ w3, double* __restrict__ pa) {
  __shared__ double red[256];
  int b = blockIdx.x, tid = threadIdx.x;
  int tix = b >> 5, slice = b & 31;
  const float* w = (tix == 0) ? w1 : (tix == 1) ? w2 : w3;
  int len = (tix == 1) ? 331776 : 6144;
  int per = len >> 5;
  int start = slice * per, end = start + per;
  double s = 0.0;
  for (int i = start + tid; i < end; i += 256) s += (double)fabsf(w[i]);
  red[tid] = s; __syncthreads();
  for (int off = 128; off > 0; off >>= 1) {
    if (tid < off) red[tid] += red[tid + off];
    __syncthreads();
  }
  if (tid == 0) pa[b] = red[0];
}

// ---------------- stats pass 2 + weight pack (merged, verified R14) --------
__global__ void stats2_pack_kernel(
    const float* __restrict__ w1, const float* __restrict__ w2, const float* __restrict__ w3,
    const double* __restrict__ pa, double* __restrict__ ps2, double* __restrict__ pc2,
    __bf16* __restrict__ w1p, __bf16* __restrict__ w2p, __bf16* __restrict__ w3p) {
  __shared__ double red[256];
  __shared__ float sdelta[3];
  int b = blockIdx.x, tid = threadIdx.x;

  if (b < 96) {   // ---- stats2, verbatim ----
    int tix = b >> 5, slice = b & 31;
    const float* w = (tix == 0) ? w1 : (tix == 1) ? w2 : w3;
    int len = (tix == 1) ? 331776 : 6144;
    double tot = 0.0;
    for (int k = 0; k < 32; ++k) tot += pa[tix * 32 + k];
    float delta = 0.7f * (float)(tot / (double)len);
    int per = len >> 5;
    int start = slice * per, end = start + per;
    double s2 = 0.0, c2 = 0.0;
    for (int i = start + tid; i < end; i += 256) {
      float aw = fabsf(w[i]);
      if (aw > delta) { s2 += (double)aw; c2 += 1.0; }
    }
    red[tid] = s2; __syncthreads();
    for (int off = 128; off > 0; off >>= 1) {
      if (tid < off) red[tid] += red[tid + off];
      __syncthreads();
    }
    if (tid == 0) ps2[b] = red[0];
    __syncthreads();
    red[tid] = c2; __syncthreads();
    for (int off = 128; off > 0; off >>= 1) {
      if (tid < off) red[tid] += red[tid + off];
      __syncthreads();
    }
    if (tid == 0) pc2[b] = red[0];
    return;
  }

  // ---- weight packing (delta-only; identical expressions) ----
  if (tid < 3) {
    double tot = 0.0;
    for (int k = 0; k < 32; ++k) tot += pa[tid * 32 + k];
    int len = (tid == 1) ? 331776 : 6144;
    sdelta[tid] = 0.7f * (float)(tot / (double)len);
  }
  __syncthreads();

  int idx = (b - 96) * 256 + tid;          // 0 .. 344063
  if (idx < 331776) {
    float delta2 = sdelta[1];
    int c = idx / 6144, rem = idx - c * 6144;
    int co = rem >> 5, r5 = rem & 31;
    int cp = r5 >> 3, lo = r5 & 7;
    int tap = c / 6, cb = c - tap * 6;
    int ci = ((cp ^ ((co >> 2) & 3)) << 3) | lo;   // source-side chunk swizzle
    int cifull = cb * 32 + ci;
    w2p[idx] = tern(w2[(co * 192 + cifull) * 9 + tap], delta2);
    return;
  }
  idx -= 331776;
  if (idx < 6144) {  // w1p, swizzled
    int co = idx >> 5, c = (idx >> 3) & 3, lo = idx & 7;
    int ci = ((c ^ ((co >> 2) & 3)) << 3) | lo;
    w1p[idx] = tern(w1[co * 32 + ci], sdelta[0]);
    return;
  }
  idx -= 6144;
  if (idx < 6144) {  // w3p, swizzled
    int kc = idx >> 11, rem = idx & 2047;
    int co = rem >> 6, c = (rem >> 3) & 7, lo = rem & 7;
    int ci = ((c ^ (co & 7)) << 3) | lo;
    w3p[idx] = tern(w3[co * 192 + kc * 64 + ci], sdelta[2]);
  }
}

// ---------------- conv1: 2-row blocks, non-union LDS -----------------------
// grid (56 h-pairs, 16 n), 256 threads (4 waves). Per-row math verbatim from
// verified R15; smA/smB persist (no reg preload); P uses conv2's epilogue
// layout (384B rows, kc*128 + (chunk^(px&7))*16).
__global__ __launch_bounds__(256)
void conv1_kernel(const float* __restrict__ x, const __bf16* __restrict__ w1p,
                  const float* __restrict__ g1, const float* __restrict__ b1,
                  const float* __restrict__ m1, const float* __restrict__ v1,
                  const double* __restrict__ ps2, const double* __restrict__ pc2,
                  const float* __restrict__ g2, const float* __restrict__ b2,
                  const float* __restrict__ m2, const float* __restrict__ v2,
                  const float* __restrict__ g3, const float* __restrict__ b3,
                  const float* __restrict__ m3, const float* __restrict__ v3,
                  float* __restrict__ sc2, float* __restrict__ sh2,
                  float* __restrict__ sc3, float* __restrict__ sh3,
                  __bf16* __restrict__ h1p) {
  __shared__ __align__(16) char smem[69632];
  __shared__ float salpha[3];
  __shared__ __align__(16) float sc1l[192];
  __shared__ __align__(16) float sh1l[192];
  char* smA = smem;           // 2 x 7168 B acts (rows r0,r1), chunk-swizzled
  char* smB = smem + 14336;   // 12288 B weights (swizzle baked in w1p)
  char* Pb  = smem + 26624;   // 43008 B P buffer (conv2 epilogue layout)
  int tid = threadIdx.x, lane = tid & 63, wave = tid >> 6;
  int bh = blockIdx.x, n = blockIdx.y;
  int h0 = bh * 2;

  for (int t = wave; t < 12; t += 4)
    glds16((const char*)w1p + t * 1024 + lane * 16, smB + t * 1024);

  // alphas (identical k-order) + BN1 consts into LDS
  if (tid < 3) {
    double s2 = 0.0, c2 = 0.0;
    for (int k = 0; k < 32; ++k) {
      s2 += ps2[tid * 32 + k];
      c2 += pc2[tid * 32 + k];
    }
    salpha[tid] = (float)(s2 / fmax(c2, 1.0));
  }
  __syncthreads();
  if (tid < 192) {
    float rs = rsqrtf(v1[tid] + EPSBN);
    sc1l[tid] = g1[tid] * rs * salpha[0];
    sh1l[tid] = b1[tid] - m1[tid] * g1[tid] * rs;
  }
  // block (0,0): produce conv2/conv3 BN consts (stream order covers conv2)
  if (bh == 0 && n == 0) {
    if (tid < 192) {
      float rs = rsqrtf(v2[tid] + EPSBN);
      sc2[tid] = g2[tid] * rs * salpha[1];
      sh2[tid] = b2[tid] - m2[tid] * g2[tid] * rs;
    } else if (tid < 224) {
      int j = tid - 192;
      float rs = rsqrtf(v3[j] + EPSBN);
      sc3[j] = g3[j] * rs * salpha[2];
      sh3[j] = b3[j] - m3[j] * g3[j] * rs;
    }
  }

  // x staging for both rows (identical scheme to verified R15)
  const float* xn = x + (long)n * 401408;   // + ci*12544 + h*112 + w
#pragma unroll
  for (int i = 0; i < 7; ++i) {
    int g = i * 256 + tid;
    if (g < 1792) {
      int r = (g >= 896) ? 1 : 0;
      int gg = g - r * 896;
      int ci0 = (gg / 112) * 4, w = gg - (gg / 112) * 112;
      const float* p = xn + ci0 * 12544 + (h0 + r) * 112 + w;
      bf16x4 v;
      v[0] = (__bf16)p[0];
      v[1] = (__bf16)p[12544];
      v[2] = (__bf16)p[25088];
      v[3] = (__bf16)p[37632];
      int col = ((ci0 >> 3) ^ ((w >> 2) & 3));
      *(bf16x4*)(smA + r * 7168 + w * 64 + (col << 4) + (ci0 & 7) * 2) = v;
    }
  }
  __syncthreads();

  int mrow = lane & 15, quad = lane >> 4;
  int col16 = (quad ^ ((mrow >> 2) & 3)) * 16;
  int c0 = wave * 48;

  bf16x8 aw[3];
#pragma unroll
  for (int ic = 0; ic < 3; ++ic)
    aw[ic] = *(const bf16x8*)(smB + (c0 + ic * 16 + mrow) * 64 + col16);

#pragma unroll
  for (int r = 0; r < 2; ++r) {
    int h = h0 + r;

    f32x4 acc[7][3];
#pragma unroll
    for (int jp = 0; jp < 7; ++jp)
#pragma unroll
      for (int ic = 0; ic < 3; ++ic) acc[jp][ic] = (f32x4)0.0f;

#pragma unroll
    for (int jp = 0; jp < 7; ++jp) {
      bf16x8 bv = *(const bf16x8*)(smA + r * 7168 + (jp * 16 + mrow) * 64 + col16);
#pragma unroll
      for (int ic = 0; ic < 3; ++ic)
        acc[jp][ic] = __builtin_amdgcn_mfma_f32_16x16x32_bf16(aw[ic], bv, acc[jp][ic], 0, 0, 0);
    }

    // epilogue: BN + ReLU6 -> P LDS (conv2 layout: 384B rows, kc/chunk swz)
#pragma unroll
    for (int ic = 0; ic < 3; ++ic) {
      int co0 = c0 + ic * 16 + quad * 4;
      float4 sc = *(const float4*)(sc1l + co0);
      float4 sh = *(const float4*)(sh1l + co0);
      int kc = co0 >> 6, c6 = co0 & 63;
      int chunk = c6 >> 3, off = c6 & 7;
#pragma unroll
      for (int jp = 0; jp < 7; ++jp) {
        int px = jp * 16 + mrow;
        bf16x4 o;
        o[0] = (__bf16)fminf(fmaxf(acc[jp][ic][0] * sc.x + sh.x, 0.0f), 6.0f);
        o[1] = (__bf16)fminf(fmaxf(acc[jp][ic][1] * sc.y + sh.y, 0.0f), 6.0f);
        o[2] = (__bf16)fminf(fmaxf(acc[jp][ic][2] * sc.z + sh.z, 0.0f), 6.0f);
        o[3] = (__bf16)fminf(fmaxf(acc[jp][ic][3] * sc.w + sh.w, 0.0f), 6.0f);
        *(bf16x4*)(Pb + px * 384 + kc * 128 + ((chunk ^ (px & 7)) * 16) + off * 2) = o;
      }
    }
    asm volatile("s_waitcnt lgkmcnt(0)" ::: "memory");
    __builtin_amdgcn_s_barrier();
    __builtin_amdgcn_sched_barrier(0);

    // coalesced copy-out: interior row = contiguous 2688 x 16B
    // h1p chunk c = w*24 + lch  ->  Pb[w*384 + (lch>>3)*128 + ((lch&7)^(w&7))*16]
    __bf16* obase = h1p + ((long)(n * 114 + h + 1) * 114 + 1) * 192;
#pragma unroll
    for (int i = 0; i < 11; ++i) {
      int c = i * 256 + tid;
      if (c < 2688) {
        int w = c / 24, lch = c - w * 24;
        float4 v = *(const float4*)(Pb + w * 384 + (lch >> 3) * 128 +
                                    (((lch & 7) ^ (w & 7)) << 4));
        *(float4*)((char*)obase + c * 16) = v;
      }
    }

    // fused border zeroing for this row (+ top/bottom full rows)
    float4 z = make_float4(0.f, 0.f, 0.f, 0.f);
    if (tid < 48) {
      int px = (tid < 24) ? 0 : 113;
      int c8 = (tid < 24) ? tid : tid - 24;
      *(float4*)((char*)h1p + ((long)((n * 114 + h + 1) * 114 + px) * 384) + c8 * 16) = z;
    }
    if (h == 0) {
      for (int c = tid; c < 2736; c += 256)
        *(float4*)((char*)h1p + (long)(n * 114) * 114 * 384 + c * 16) = z;
    }
    if (h == 111) {
      for (int c = tid; c < 2736; c += 256)
        *(float4*)((char*)h1p + (long)(n * 114 + 113) * 114 * 384 + c * 16) = z;
    }

    if (r == 0) {   // Pb reads consumed before row 1 overwrites it
      asm volatile("s_waitcnt lgkmcnt(0)" ::: "memory");
      __builtin_amdgcn_s_barrier();
      __builtin_amdgcn_sched_barrier(0);
    }
  }
}

// ---------------- conv2+conv3 fused (byte-identical to verified R13-R15) ---
#define STAGE_W(TAP, CB, B) do {                                              \
  _Pragma("unroll")                                                           \
  for (int it_ = 0; it_ < 3; ++it_) {                                         \
    int t_ = wave + it_ * 4;                                                  \
    glds16(w2b + (long)((TAP) * 6 + (CB)) * 12288 + t_ * 1024 + lane * 16,    \
           smBb + (B) * 12288 + t_ * 1024);                                   \
  }                                                                           \
} while (0)

#define STAGE_A(CB) do {                                                      \
  _Pragma("unroll")                                                           \
  for (int it_ = 0; it_ < 8; ++it_)                                           \
    if (aoff[it_] >= 0)                                                       \
      glds16(h1b + aoff[it_] + (CB) * 64, smAb + (wave + it_ * 4) * 1024);    \
} while (0)

__global__ __launch_bounds__(256, 2)
void conv2_kernel(const __bf16* __restrict__ h1p, const __bf16* __restrict__ w2p,
                  const float* __restrict__ scale2, const float* __restrict__ shift2,
                  const __bf16* __restrict__ w3p,
                  const float* __restrict__ scale3, const float* __restrict__ shift3,
                  const float* __restrict__ x, float* __restrict__ out) {
  __shared__ __align__(16) char smem[53760];
  char* smAb = smem;            // 29184 B act window (main loop)
  char* smBb = smem + 29184;    // 2 x 12288 B weights, double-buffered
  char* Pb   = smem;            // 43008 B P-row (epilogue union)
  int tid = threadIdx.x, lane = tid & 63, wave = tid >> 6;
  int bh = blockIdx.x, n = blockIdx.y;
  int h0 = bh * 2;

  // A staging source offsets (bytes, + cb*64 at use); slot s = t*64+lane
  int aoff[8];
#pragma unroll
  for (int it = 0; it < 8; ++it) {
    int t = wave + it * 4;
    int s = t * 64 + lane;
    if (s < 1824) {
      int q = s >> 2, c = s & 3;
      int q_log = c ^ ((q >> 2) & 3);
      int prow = q / 114, pcol = q - prow * 114;
      aoff[it] = ((n * 114 + h0 + prow) * 114 + pcol) * 384 + q_log * 16;
    } else {
      aoff[it] = -1;
    }
  }

  int pg = wave >> 1, cg = wave & 1;
  int mrow = lane & 15, quad = lane >> 4;
  int col16 = (quad ^ ((mrow >> 2) & 3)) * 16;
  const char* h1b = (const char*)h1p;
  const char* w2b = (const char*)w2p;

  f32x4 acc[7][6];
#pragma unroll
  for (int jp = 0; jp < 7; ++jp)
#pragma unroll
    for (int ic = 0; ic < 6; ++ic) acc[jp][ic] = (f32x4)0.0f;

  // prologue: A(0) + W0->buf0 in flight before the first tap
  STAGE_A(0);
  STAGE_W(0, 0, 0);

  for (int cb = 0; cb < 6; ++cb) {
#pragma unroll
    for (int tap = 0; tap < 9; ++tap) {
      // gate own loads BEFORE the barrier (R8 pattern) -> block-wide visible
      asm volatile("s_waitcnt vmcnt(0)" ::: "memory");
      __builtin_amdgcn_s_barrier();
      __builtin_amdgcn_sched_barrier(0);
      if (tap <= 7)
        STAGE_W(tap + 1, cb, (tap + 1) & 1);   // buf last read at tap-1: idle

      const char* bbuf = smBb + (tap & 1) * 12288;
      bf16x8 aw[6];
#pragma unroll
      for (int ic = 0; ic < 6; ++ic)
        aw[ic] = *(const bf16x8*)(bbuf + (cg * 96 + ic * 16 + mrow) * 64 + col16);

      int dy = tap / 3, dx = tap - dy * 3;
      int base = (pg + dy) * 114 + dx;
      __builtin_amdgcn_s_setprio(1);
#pragma unroll
      for (int jp = 0; jp < 7; ++jp) {
        int row = base + jp * 16 + mrow;
        bf16x8 av = *(const bf16x8*)(smAb + row * 64 +
                                     ((quad ^ ((row >> 2) & 3)) * 16));
#pragma unroll
        for (int ic = 0; ic < 6; ++ic)
          acc[jp][ic] = __builtin_amdgcn_mfma_f32_16x16x32_bf16(aw[ic], av, acc[jp][ic], 0, 0, 0);
      }
      __builtin_amdgcn_s_setprio(0);
    }

    // seam: all waves issued tap-8 MFMAs at this barrier -> smA reads done
    if (cb < 5) {
      __builtin_amdgcn_s_barrier();
      __builtin_amdgcn_sched_barrier(0);
      STAGE_A(cb + 1);
      STAGE_W(0, cb + 1, 0);
    }
  }

  // ---------------- fused conv3 epilogue ----------------------------------
  asm volatile("s_waitcnt lgkmcnt(0)" ::: "memory");
  __builtin_amdgcn_s_barrier();
  __builtin_amdgcn_sched_barrier(0);

  // per-lane conv3 BN params: co = (wave&1)*16 + mrow
  int cohalf = wave & 1;
  int co3 = cohalf * 16 + mrow;
  float sc3v = scale3[co3], sh3v = shift3[co3];
  int fbase = (wave >> 1) * 4;             // waves 0,1 -> frags 0..3; 2,3 -> 4..6
  int swz = mrow & 7;

  // w3 b-fragments straight from global (same bits as the old LDS stage)
  bf16x8 wb0[3], wb1[3];
#pragma unroll
  for (int kc = 0; kc < 3; ++kc) {
    wb0[kc] = *(const bf16x8*)((const char*)w3p + kc * 4096 +
                               (cohalf * 16 + mrow) * 128 + ((quad ^ swz) * 16));
    wb1[kc] = *(const bf16x8*)((const char*)w3p + kc * 4096 +
                               (cohalf * 16 + mrow) * 128 + (((4 + quad) ^ swz) * 16));
  }

#pragma unroll
  for (int rg = 0; rg < 2; ++rg) {
    if (pg == rg) {
      // write this wave's half (cg) of P-row rg
#pragma unroll
      for (int ic = 0; ic < 6; ++ic) {
        int co0 = cg * 96 + ic * 16 + quad * 4;
        float4 sc = *(const float4*)(scale2 + co0);
        float4 sh = *(const float4*)(shift2 + co0);
        int kc = co0 >> 6, c6 = co0 & 63;
        int chunk = c6 >> 3, off = c6 & 7;
#pragma unroll
        for (int jp = 0; jp < 7; ++jp) {
          int px = jp * 16 + mrow;
          bf16x4 o;
          o[0] = (__bf16)fminf(fmaxf(acc[jp][ic][0] * sc.x + sh.x, 0.0f), 6.0f);
          o[1] = (__bf16)fminf(fmaxf(acc[jp][ic][1] * sc.y + sh.y, 0.0f), 6.0f);
          o[2] = (__bf16)fminf(fmaxf(acc[jp][ic][2] * sc.z + sh.z, 0.0f), 6.0f);
          o[3] = (__bf16)fminf(fmaxf(acc[jp][ic][3] * sc.w + sh.w, 0.0f), 6.0f);
          *(bf16x4*)(Pb + px * 384 + kc * 128 + ((chunk ^ (px & 7)) * 16) + off * 2) = o;
        }
      }
    }
    asm volatile("s_waitcnt lgkmcnt(0)" ::: "memory");
    __builtin_amdgcn_s_barrier();
    __builtin_amdgcn_sched_barrier(0);

    // conv3 on row rg: wave covers co 16*(wave&1).. and px frags fbase..(+3|+2)
    f32x4 acc3[4];
#pragma unroll
    for (int f = 0; f < 4; ++f) acc3[f] = (f32x4)0.0f;
#pragma unroll
    for (int kc = 0; kc < 3; ++kc) {
#pragma unroll
      for (int f = 0; f < 4; ++f) {
        if (fbase + f < 7) {
          int pr = (fbase + f) * 16 + mrow;
          bf16x8 a0 = *(const bf16x8*)(Pb + pr * 384 + kc * 128 + ((quad ^ swz) * 16));
          bf16x8 a1 = *(const bf16x8*)(Pb + pr * 384 + kc * 128 + (((4 + quad) ^ swz) * 16));
          acc3[f] = __builtin_amdgcn_mfma_f32_16x16x32_bf16(a0, wb0[kc], acc3[f], 0, 0, 0);
          acc3[f] = __builtin_amdgcn_mfma_f32_16x16x32_bf16(a1, wb1[kc], acc3[f], 0, 0, 0);
        }
      }
    }
    // BN (no act) + residual, fp32 float4 stores to NCHW
    int h = h0 + rg;
    long obase = ((long)(n * 32 + co3) * 112 + h) * 112;
    const float* xb = x + obase;
    float* ob = out + obase;
#pragma unroll
    for (int f = 0; f < 4; ++f) {
      if (fbase + f < 7) {
        int w0 = (fbase + f) * 16 + quad * 4;
        float4 xv = *(const float4*)(xb + w0);
        float4 o;
        o.x = acc3[f][0] * sc3v + sh3v + xv.x;
        o.y = acc3[f][1] * sc3v + sh3v + xv.y;
        o.z = acc3[f][2] * sc3v + sh3v + xv.z;
        o.w = acc3[f][3] * sc3v + sh3v + xv.w;
        *(float4*)(ob + w0) = o;
      }
    }
    if (rg == 0) {
      asm volatile("s_waitcnt lgkmcnt(0)" ::: "memory");
      __builtin_amdgcn_s_barrier();
      __builtin_amdgcn_sched_barrier(0);
    }
  }
}

// ---------------- launch ---------------------------------------------------
extern "C" void kernel_launch(void* const* d_in, const int* in_sizes, int n_in,
                              void* d_out, int out_size, void* d_ws, size_t ws_size,
                              hipStream_t stream) {
  const float* x  = (const float*)d_in[0];
  const float* w1 = (const float*)d_in[1];
  const float* g1 = (const float*)d_in[2];
  const float* b1 = (const float*)d_in[3];
  const float* m1 = (const float*)d_in[4];
  const float* v1 = (const float*)d_in[5];
  const float* w2 = (const float*)d_in[6];
  const float* g2 = (const float*)d_in[7];
  const float* b2 = (const float*)d_in[8];
  const float* m2 = (const float*)d_in[9];
  const float* v2 = (const float*)d_in[10];
  const float* w3 = (const float*)d_in[11];
  const float* g3 = (const float*)d_in[12];
  const float* b3 = (const float*)d_in[13];
  const float* m3 = (const float*)d_in[14];
  const float* v3 = (const float*)d_in[15];
  float* out = (float*)d_out;

  char* ws = (char*)d_ws;
  double* pa    = (double*)(ws + 256);        // 96 doubles
  double* ps2   = (double*)(ws + 1024);
  double* pc2   = (double*)(ws + 1792);
  float* sc2 = (float*)(ws + 4096);
  float* sh2 = (float*)(ws + 4864);
  float* sc3 = (float*)(ws + 5632);
  float* sh3 = (float*)(ws + 5760);
  __bf16* w1p = (__bf16*)(ws + 8192);         // 12288 B
  __bf16* w3p = (__bf16*)(ws + 20480);        // 12288 B
  __bf16* w2p = (__bf16*)(ws + 32768);        // 663552 B
  __bf16* h1p = (__bf16*)(ws + (1 << 20));    // 79847424 B (padded NHWC)

  hipLaunchKernelGGL(stats_pass1, dim3(96), dim3(256), 0, stream, w1, w2, w3, pa);
  hipLaunchKernelGGL(stats2_pack_kernel, dim3(1440), dim3(256), 0, stream,
                     w1, w2, w3, pa, ps2, pc2, w1p, w2p, w3p);
  hipLaunchKernelGGL(conv1_kernel, dim3(56, 16), dim3(256), 0, stream, x, w1p,
                     g1, b1, m1, v1, ps2, pc2, g2, b2, m2, v2, g3, b3, m3, v3,
                     sc2, sh2, sc3, sh3, h1p);
  hipLaunchKernelGGL(conv2_kernel, dim3(56, 16), dim3(256), 0, stream, h1p, w2p, sc2, sh2,
                     w3p, sc3, sh3, x, out);
}